// Round 2
// baseline (201.775 us; speedup 1.0000x reference)
//
#include <hip/hip_runtime.h>

#define P_N 40000
#define M_N 100
#define NB1 2500   // blocks for moment kernel (4 waves each -> 10000 waves)

// ---------------- Kernel 1: per-pillar means + global feature moments ----------------
// wave = pillar (4 pillars per wave over grid-stride), float2 point loads (50 lanes).

__device__ __forceinline__ void acc_point(float (&a1)[9], float (&a2)[45], const float f[9]) {
  #pragma unroll
  for (int c = 0; c < 9; ++c) a1[c] += f[c];
  int k = 0;
  #pragma unroll
  for (int c = 0; c < 9; ++c) {
    #pragma unroll
    for (int c2 = c; c2 < 9; ++c2) {
      a2[k] = fmaf(f[c], f[c2], a2[k]);
      ++k;
    }
  }
}

__global__ __launch_bounds__(256) void k_moments(
    const float* __restrict__ px, const float* __restrict__ py,
    const float* __restrict__ pz, const float* __restrict__ pi,
    const int* __restrict__ npp, const int* __restrict__ coors,
    float* __restrict__ partials, float* __restrict__ means)
{
  const int lane = threadIdx.x & 63;
  const int wid  = threadIdx.x >> 6;

  float a1[9]; float a2[45];
  #pragma unroll
  for (int i = 0; i < 9; ++i) a1[i] = 0.f;
  #pragma unroll
  for (int i = 0; i < 45; ++i) a2[i] = 0.f;

  const bool act = lane < 50;
  const int  li  = act ? lane : 0;

  #pragma unroll 1
  for (int it = 0; it < 4; ++it) {
    const int p = __builtin_amdgcn_readfirstlane(blockIdx.x * 4 + wid + it * (NB1 * 4));

    const float2* xr2 = (const float2*)(px + (size_t)p * M_N);
    const float2* yr2 = (const float2*)(py + (size_t)p * M_N);
    const float2* zr2 = (const float2*)(pz + (size_t)p * M_N);
    const float2* ir2 = (const float2*)(pi + (size_t)p * M_N);

    float2 x2 = xr2[li], y2 = yr2[li], z2 = zr2[li], i2 = ir2[li];
    if (!act) { x2.x = x2.y = 0.f; y2.x = y2.y = 0.f; z2.x = z2.y = 0.f; i2.x = i2.y = 0.f; }

    // full (unmasked) sums for the means
    float sx = x2.x + x2.y, sy = y2.x + y2.y, sz = z2.x + z2.y;
    #pragma unroll
    for (int off = 32; off; off >>= 1) {
      sx += __shfl_xor(sx, off);
      sy += __shfl_xor(sy, off);
      sz += __shfl_xor(sz, off);
    }
    const int n  = npp[p];
    const int nc = n < 1 ? 1 : n;
    const float inv = 1.f / (float)nc;
    const float mx = sx * inv, my = sy * inv, mz = sz * inv;

    const int c2 = coors[p * 4 + 2], c3 = coors[p * 4 + 3];
    const float xb = fmaf((float)c3, 0.16f, 0.08f);            // X0 = 0
    const float yb = fmaf((float)c2, 0.16f, 0.08f - 39.68f);   // Y0 = -39.68

    if (lane == 0) {
      means[p * 4 + 0] = mx;
      means[p * 4 + 1] = my;
      means[p * 4 + 2] = mz;
    }

    // point slots 2*lane, 2*lane+1 (lanes >= 50 have slot >= 100 > n, auto-invalid)
    if (2 * lane < n) {
      float f[9] = {x2.x, y2.x, z2.x, i2.x, x2.x - mx, y2.x - my, z2.x - mz, xb, yb};
      acc_point(a1, a2, f);
    }
    if (2 * lane + 1 < n) {
      float f[9] = {x2.y, y2.y, z2.y, i2.y, x2.y - mx, y2.y - my, z2.y - mz, xb, yb};
      acc_point(a1, a2, f);
    }
  }

  // wave reduce all 54 accumulators
  #pragma unroll
  for (int off = 32; off; off >>= 1) {
    #pragma unroll
    for (int i = 0; i < 9; ++i)  a1[i] += __shfl_xor(a1[i], off);
    #pragma unroll
    for (int i = 0; i < 45; ++i) a2[i] += __shfl_xor(a2[i], off);
  }

  __shared__ float red[4][54];
  if (lane == 0) {
    #pragma unroll
    for (int i = 0; i < 9; ++i)  red[wid][i]     = a1[i];
    #pragma unroll
    for (int i = 0; i < 45; ++i) red[wid][9 + i] = a2[i];
  }
  __syncthreads();
  if (threadIdx.x < 54) {
    const int t = threadIdx.x;
    partials[blockIdx.x * 54 + t] = red[0][t] + red[1][t] + red[2][t] + red[3][t];
  }
}

// ---------------- Kernel 2: reduce partials -> per-channel BN scale/shift ----------------

__global__ __launch_bounds__(1024) void k_stats(
    const float* __restrict__ partials, const float* __restrict__ W,
    const float* __restrict__ gamma, const float* __restrict__ beta,
    float* __restrict__ scale, float* __restrict__ shift)
{
  __shared__ float red[18 * 54];
  __shared__ float mom[54];
  const int tid = threadIdx.x;

  if (tid < 18 * 54) {
    const int c = tid % 54, g = tid / 54;
    float s = 0.f;
    for (int b = g; b < NB1; b += 18) s += partials[b * 54 + c];
    red[tid] = s;
  }
  __syncthreads();
  if (tid < 54) {
    float s = 0.f;
    #pragma unroll
    for (int g = 0; g < 18; ++g) s += red[g * 54 + tid];
    mom[tid] = s;
  }
  __syncthreads();

  if (tid < 64) {
    float w[9];
    #pragma unroll
    for (int c = 0; c < 9; ++c) w[c] = W[c * 64 + tid];
    const float invN = 1.f / ((float)P_N * (float)M_N);
    float mu = 0.f;
    #pragma unroll
    for (int c = 0; c < 9; ++c) mu += mom[c] * w[c];
    mu *= invN;
    float e2 = 0.f;
    int k = 0;
    #pragma unroll
    for (int c = 0; c < 9; ++c) {
      #pragma unroll
      for (int c2 = c; c2 < 9; ++c2) {
        const float t = w[c] * w[c2] * mom[9 + k];
        e2 += (c == c2) ? t : 2.f * t;
        ++k;
      }
    }
    e2 *= invN;
    float var = e2 - mu * mu;
    var = var < 0.f ? 0.f : var;
    const float sc = gamma[tid] * rsqrtf(var + 1e-5f);
    const float sh = fmaf(-mu, sc, beta[tid]);
    scale[tid] = sc;
    shift[tid] = sh;
  }
}

// ---------------- Kernel 3: fused linear+BN+ReLU+max ----------------
// wave = pillar. Lanes 0..24 stage the full row (float4, lane-varying -> vector loads)
// into per-wave LDS; then lane = channel consumes points via LDS broadcast.

__global__ __launch_bounds__(256) void k_out(
    const float* __restrict__ px, const float* __restrict__ py,
    const float* __restrict__ pz, const float* __restrict__ pi,
    const int* __restrict__ npp, const int* __restrict__ coors,
    const float* __restrict__ W, const float* __restrict__ scale,
    const float* __restrict__ shift, const float* __restrict__ means,
    float* __restrict__ out)
{
  const int lane = threadIdx.x & 63;
  const int wid  = threadIdx.x >> 6;
  const int d    = lane;

  __shared__ float4 lsx[4][26], lsy[4][26], lsz[4][26], lsi[4][26];

  const int p = __builtin_amdgcn_readfirstlane(blockIdx.x * 4 + wid);

  // stage the pillar's rows: lane-varying float4 loads (25 per array)
  {
    const float4* xr4 = (const float4*)(px + (size_t)p * M_N);
    const float4* yr4 = (const float4*)(py + (size_t)p * M_N);
    const float4* zr4 = (const float4*)(pz + (size_t)p * M_N);
    const float4* ir4 = (const float4*)(pi + (size_t)p * M_N);
    if (lane < 25) {
      lsx[wid][lane] = xr4[lane];
      lsy[wid][lane] = yr4[lane];
      lsz[wid][lane] = zr4[lane];
      lsi[wid][lane] = ir4[lane];
    }
  }

  const float sc = scale[d], sh = shift[d];
  float w[9];
  #pragma unroll
  for (int c = 0; c < 9; ++c) w[c] = W[c * 64 + d];
  const float sA = sc * (w[0] + w[4]);
  const float sB = sc * (w[1] + w[5]);
  const float sC = sc * (w[2] + w[6]);
  const float sD = sc * w[3];
  const float s4 = sc * w[4], s5 = sc * w[5], s6 = sc * w[6];
  const float s7 = sc * w[7], s8 = sc * w[8];

  const int n  = npp[p];
  const int c2 = coors[p * 4 + 2], c3 = coors[p * 4 + 3];
  const float mx = means[p * 4 + 0], my = means[p * 4 + 1], mz = means[p * 4 + 2];
  const float xb = fmaf((float)c3, 0.16f, 0.08f);
  const float yb = fmaf((float)c2, 0.16f, 0.08f - 39.68f);

  float sE = sh;
  sE = fmaf(-mx, s4, sE);
  sE = fmaf(-my, s5, sE);
  sE = fmaf(-mz, s6, sE);
  sE = fmaf( xb, s7, sE);
  sE = fmaf( yb, s8, sE);

  __syncthreads();

  const int v = n < M_N ? n : M_N;
  // masked points contribute h = shift; there is always one when v < M
  float acc = (v < M_N) ? sh : -3.0e38f;

  const float4* lx = lsx[wid];
  const float4* ly = lsy[wid];
  const float4* lz = lsz[wid];
  const float4* li = lsi[wid];

  const int v4 = v >> 2;
  #pragma unroll 2
  for (int c = 0; c < v4; ++c) {
    const float4 ax = lx[c], ay = ly[c], az = lz[c], ai = li[c];
    float t0 = fmaf(ax.x, sA, sE); t0 = fmaf(ay.x, sB, t0); t0 = fmaf(az.x, sC, t0); t0 = fmaf(ai.x, sD, t0);
    float t1 = fmaf(ax.y, sA, sE); t1 = fmaf(ay.y, sB, t1); t1 = fmaf(az.y, sC, t1); t1 = fmaf(ai.y, sD, t1);
    float t2 = fmaf(ax.z, sA, sE); t2 = fmaf(ay.z, sB, t2); t2 = fmaf(az.z, sC, t2); t2 = fmaf(ai.z, sD, t2);
    float t3 = fmaf(ax.w, sA, sE); t3 = fmaf(ay.w, sB, t3); t3 = fmaf(az.w, sC, t3); t3 = fmaf(ai.w, sD, t3);
    acc = fmaxf(acc, fmaxf(fmaxf(t0, t1), fmaxf(t2, t3)));
  }
  const float* fx = (const float*)lx;
  const float* fy = (const float*)ly;
  const float* fz = (const float*)lz;
  const float* fi = (const float*)li;
  for (int m = v4 * 4; m < v; ++m) {
    float t = fmaf(fx[m], sA, sE);
    t = fmaf(fy[m], sB, t);
    t = fmaf(fz[m], sC, t);
    t = fmaf(fi[m], sD, t);
    acc = fmaxf(acc, t);
  }

  // max(relu(h)) == relu(max(h))
  out[(size_t)p * 64 + d] = fmaxf(acc, 0.f);
}

// ---------------- launch ----------------

extern "C" void kernel_launch(void* const* d_in, const int* in_sizes, int n_in,
                              void* d_out, int out_size, void* d_ws, size_t ws_size,
                              hipStream_t stream) {
  const float* px    = (const float*)d_in[0];
  const float* py    = (const float*)d_in[1];
  const float* pz    = (const float*)d_in[2];
  const float* pi    = (const float*)d_in[3];
  const int*   npp   = (const int*)d_in[4];
  const int*   coors = (const int*)d_in[5];
  const float* W     = (const float*)d_in[6];
  const float* gamma = (const float*)d_in[7];
  const float* beta  = (const float*)d_in[8];
  float* out = (float*)d_out;

  float* wsf      = (float*)d_ws;
  float* partials = wsf;                    // NB1*54 = 135000 floats
  float* scale    = wsf + 135000;           // 64
  float* shift    = wsf + 135064;           // 64
  float* means    = wsf + 135168;           // 4*P_N floats (x,y,z,pad)

  k_moments<<<NB1, 256, 0, stream>>>(px, py, pz, pi, npp, coors, partials, means);
  k_stats<<<1, 1024, 0, stream>>>(partials, W, gamma, beta, scale, shift);
  k_out<<<P_N / 4, 256, 0, stream>>>(px, py, pz, pi, npp, coors, W, scale, shift, means, out);
}

// Round 3
// 123.268 us; speedup vs baseline: 1.6369x; 1.6369x over previous
//
#include <hip/hip_runtime.h>

#define P_N 40000
#define M_N 100
#define NB1 2500   // k_moments blocks (4 waves, 4 pillars/wave)

// broadcast lane l's value to all lanes (l wave-uniform) -> SGPR
__device__ __forceinline__ float rl(float v, int l) {
  return __uint_as_float(__builtin_amdgcn_readlane(__float_as_uint(v), l));
}

// ---------------- Kernel 1: per-pillar means + global feature moments ----------------

__device__ __forceinline__ void acc_point(float (&a1)[9], float (&a2)[45], const float f[9]) {
  #pragma unroll
  for (int c = 0; c < 9; ++c) a1[c] += f[c];
  int k = 0;
  #pragma unroll
  for (int c = 0; c < 9; ++c) {
    #pragma unroll
    for (int c2 = c; c2 < 9; ++c2) {
      a2[k] = fmaf(f[c], f[c2], a2[k]);
      ++k;
    }
  }
}

__global__ __launch_bounds__(256) void k_moments(
    const float* __restrict__ px, const float* __restrict__ py,
    const float* __restrict__ pz, const float* __restrict__ pi,
    const int* __restrict__ npp, const int* __restrict__ coors,
    float* __restrict__ partials, float* __restrict__ means)
{
  const int lane = threadIdx.x & 63;
  const int wid  = threadIdx.x >> 6;

  float a1[9]; float a2[45];
  #pragma unroll
  for (int i = 0; i < 9; ++i) a1[i] = 0.f;
  #pragma unroll
  for (int i = 0; i < 45; ++i) a2[i] = 0.f;

  const bool act = lane < 50;
  const int pbase = __builtin_amdgcn_readfirstlane(blockIdx.x * 4 + wid);

  float2 X0{},Y0{},Z0{},I0{}, X1{},Y1{},Z1{},I1{}, X2{},Y2{},Z2{},I2{}, X3{},Y3{},Z3{},I3{};
  int N0,N1,N2,N3, A0,A1_,A2_,A3, B0,B1,B2,B3;

  // load all 4 pillars' rows + scalars up front (one latency exposure)
  #define LOADM(IT, XV,YV,ZV,IV, NN, CA, CB) { \
    const int p_ = pbase + (IT) * 10000; \
    if (act) { \
      XV = ((const float2*)(px + (size_t)p_ * M_N))[lane]; \
      YV = ((const float2*)(py + (size_t)p_ * M_N))[lane]; \
      ZV = ((const float2*)(pz + (size_t)p_ * M_N))[lane]; \
      IV = ((const float2*)(pi + (size_t)p_ * M_N))[lane]; \
    } \
    NN = npp[p_]; CA = coors[p_ * 4 + 2]; CB = coors[p_ * 4 + 3]; }

  LOADM(0, X0,Y0,Z0,I0, N0, A0, B0)
  LOADM(1, X1,Y1,Z1,I1, N1, A1_, B1)
  LOADM(2, X2,Y2,Z2,I2, N2, A2_, B2)
  LOADM(3, X3,Y3,Z3,I3, N3, A3, B3)

  #define COMPM(IT, XV,YV,ZV,IV, NN, CA, CB) { \
    const int p_ = pbase + (IT) * 10000; \
    float sx = act ? (XV.x + XV.y) : 0.f; \
    float sy = act ? (YV.x + YV.y) : 0.f; \
    float sz = act ? (ZV.x + ZV.y) : 0.f; \
    _Pragma("unroll") \
    for (int off = 32; off; off >>= 1) { \
      sx += __shfl_xor(sx, off); sy += __shfl_xor(sy, off); sz += __shfl_xor(sz, off); \
    } \
    const int nc = NN < 1 ? 1 : NN; \
    const float inv = 1.f / (float)nc; \
    const float mx = sx * inv, my = sy * inv, mz = sz * inv; \
    const float xb = fmaf((float)CB, 0.16f, 0.08f); \
    const float yb = fmaf((float)CA, 0.16f, 0.08f - 39.68f); \
    if (lane == 0) { \
      means[p_ * 4 + 0] = mx; means[p_ * 4 + 1] = my; means[p_ * 4 + 2] = mz; \
    } \
    if (2 * lane < NN) { \
      float f[9] = {XV.x, YV.x, ZV.x, IV.x, XV.x - mx, YV.x - my, ZV.x - mz, xb, yb}; \
      acc_point(a1, a2, f); \
    } \
    if (2 * lane + 1 < NN) { \
      float f[9] = {XV.y, YV.y, ZV.y, IV.y, XV.y - mx, YV.y - my, ZV.y - mz, xb, yb}; \
      acc_point(a1, a2, f); \
    } }

  COMPM(0, X0,Y0,Z0,I0, N0, A0, B0)
  COMPM(1, X1,Y1,Z1,I1, N1, A1_, B1)
  COMPM(2, X2,Y2,Z2,I2, N2, A2_, B2)
  COMPM(3, X3,Y3,Z3,I3, N3, A3, B3)

  // wave reduce all 54 accumulators
  #pragma unroll
  for (int off = 32; off; off >>= 1) {
    #pragma unroll
    for (int i = 0; i < 9; ++i)  a1[i] += __shfl_xor(a1[i], off);
    #pragma unroll
    for (int i = 0; i < 45; ++i) a2[i] += __shfl_xor(a2[i], off);
  }

  __shared__ float red[4][54];
  if (lane == 0) {
    #pragma unroll
    for (int i = 0; i < 9; ++i)  red[wid][i]     = a1[i];
    #pragma unroll
    for (int i = 0; i < 45; ++i) red[wid][9 + i] = a2[i];
  }
  __syncthreads();
  if (threadIdx.x < 54) {
    const int t = threadIdx.x;
    partials[blockIdx.x * 54 + t] = red[0][t] + red[1][t] + red[2][t] + red[3][t];
  }
}

// ---------------- Kernel 1b: reduce partials -> 54 moments (54 blocks) ----------------

__global__ __launch_bounds__(256) void k_red(
    const float* __restrict__ partials, float* __restrict__ moments)
{
  const int c = blockIdx.x;
  float s = 0.f;
  for (int b = threadIdx.x; b < NB1; b += 256) s += partials[b * 54 + c];
  #pragma unroll
  for (int off = 32; off; off >>= 1) s += __shfl_xor(s, off);
  __shared__ float r4[4];
  const int lane = threadIdx.x & 63, wid = threadIdx.x >> 6;
  if (lane == 0) r4[wid] = s;
  __syncthreads();
  if (threadIdx.x == 0) moments[c] = r4[0] + r4[1] + r4[2] + r4[3];
}

// ---------------- Kernel 2: moments -> per-channel BN scale/shift ----------------

__global__ __launch_bounds__(64) void k_stats(
    const float* __restrict__ moments, const float* __restrict__ W,
    const float* __restrict__ gamma, const float* __restrict__ beta,
    float* __restrict__ scale, float* __restrict__ shift)
{
  const int d = threadIdx.x;
  float mom[54];
  #pragma unroll
  for (int i = 0; i < 54; ++i) mom[i] = moments[i];

  float w[9];
  #pragma unroll
  for (int c = 0; c < 9; ++c) w[c] = W[c * 64 + d];
  const float invN = 1.f / ((float)P_N * (float)M_N);
  float mu = 0.f;
  #pragma unroll
  for (int c = 0; c < 9; ++c) mu += mom[c] * w[c];
  mu *= invN;
  float e2 = 0.f;
  int k = 0;
  #pragma unroll
  for (int c = 0; c < 9; ++c) {
    #pragma unroll
    for (int c2 = c; c2 < 9; ++c2) {
      const float t = w[c] * w[c2] * mom[9 + k];
      e2 += (c == c2) ? t : 2.f * t;
      ++k;
    }
  }
  e2 *= invN;
  float var = e2 - mu * mu;
  var = var < 0.f ? 0.f : var;
  const float sc = gamma[d] * rsqrtf(var + 1e-5f);
  const float sh = fmaf(-mu, sc, beta[d]);
  scale[d] = sc;
  shift[d] = sh;
}

// ---------------- Kernel 3: fused linear+BN+ReLU+max ----------------
// wave owns 8 pillars, 2-deep software pipeline. Lanes<25 hold the rows in
// registers (float4); chunks broadcast to all lanes via v_readlane (no LDS,
// no barrier). lane = output channel.

__global__ __launch_bounds__(256) void k_out(
    const float* __restrict__ px, const float* __restrict__ py,
    const float* __restrict__ pz, const float* __restrict__ pi,
    const int* __restrict__ npp, const int* __restrict__ coors,
    const float* __restrict__ W, const float* __restrict__ scale,
    const float* __restrict__ shift, const float* __restrict__ means,
    float* __restrict__ out)
{
  const int lane = threadIdx.x & 63;
  const int wid  = threadIdx.x >> 6;
  const int d    = lane;

  const float sc = scale[d], sh = shift[d];
  float w[9];
  #pragma unroll
  for (int c = 0; c < 9; ++c) w[c] = W[c * 64 + d];
  const float sA = sc * (w[0] + w[4]);
  const float sB = sc * (w[1] + w[5]);
  const float sC = sc * (w[2] + w[6]);
  const float sD = sc * w[3];
  const float s4 = sc * w[4], s5 = sc * w[5], s6 = sc * w[6];
  const float s7 = sc * w[7], s8 = sc * w[8];

  const int pb = __builtin_amdgcn_readfirstlane((blockIdx.x * 4 + wid) * 8);

  float4 Ax{}, Ay{}, Az{}, Ai{}, Bx{}, By{}, Bz{}, Bi{};
  int An = 0, Ac2 = 0, Ac3 = 0, Bn = 0, Bc2 = 0, Bc3 = 0;
  float Amx = 0, Amy = 0, Amz = 0, Bmx = 0, Bmy = 0, Bmz = 0;

  #define LOADQ(S, pp) { const int p_ = (pp); \
    if (lane < 25) { \
      S##x = ((const float4*)(px + (size_t)p_ * M_N))[lane]; \
      S##y = ((const float4*)(py + (size_t)p_ * M_N))[lane]; \
      S##z = ((const float4*)(pz + (size_t)p_ * M_N))[lane]; \
      S##i = ((const float4*)(pi + (size_t)p_ * M_N))[lane]; \
    } \
    S##n  = npp[p_]; \
    S##c2 = coors[p_ * 4 + 2]; S##c3 = coors[p_ * 4 + 3]; \
    S##mx = means[p_ * 4 + 0]; S##my = means[p_ * 4 + 1]; S##mz = means[p_ * 4 + 2]; }

  #define CHUNK4(S, c, T0, T1, T2, T3) \
    float T0 = fmaf(rl(S##x.x, c), sA, sE); T0 = fmaf(rl(S##y.x, c), sB, T0); \
    T0 = fmaf(rl(S##z.x, c), sC, T0);       T0 = fmaf(rl(S##i.x, c), sD, T0); \
    float T1 = fmaf(rl(S##x.y, c), sA, sE); T1 = fmaf(rl(S##y.y, c), sB, T1); \
    T1 = fmaf(rl(S##z.y, c), sC, T1);       T1 = fmaf(rl(S##i.y, c), sD, T1); \
    float T2 = fmaf(rl(S##x.z, c), sA, sE); T2 = fmaf(rl(S##y.z, c), sB, T2); \
    T2 = fmaf(rl(S##z.z, c), sC, T2);       T2 = fmaf(rl(S##i.z, c), sD, T2); \
    float T3 = fmaf(rl(S##x.w, c), sA, sE); T3 = fmaf(rl(S##y.w, c), sB, T3); \
    T3 = fmaf(rl(S##z.w, c), sC, T3);       T3 = fmaf(rl(S##i.w, c), sD, T3);

  #define COMPQ(S, pp) { const int p_ = (pp); \
    const float xb = fmaf((float)S##c3, 0.16f, 0.08f); \
    const float yb = fmaf((float)S##c2, 0.16f, 0.08f - 39.68f); \
    float sE = sh; \
    sE = fmaf(-S##mx, s4, sE); sE = fmaf(-S##my, s5, sE); sE = fmaf(-S##mz, s6, sE); \
    sE = fmaf(xb, s7, sE);     sE = fmaf(yb, s8, sE); \
    const int v = S##n < M_N ? S##n : M_N; \
    float acc = (v < M_N) ? sh : -3.0e38f; \
    const int v4f = v >> 2, rem = v & 3; \
    for (int c = 0; c < v4f; ++c) { \
      CHUNK4(S, c, t0, t1, t2, t3) \
      acc = fmaxf(acc, fmaxf(fmaxf(t0, t1), fmaxf(t2, t3))); \
    } \
    if (rem) { \
      CHUNK4(S, v4f, u0, u1, u2, u3) \
      acc = fmaxf(acc, u0); \
      if (rem > 1) acc = fmaxf(acc, u1); \
      if (rem > 2) acc = fmaxf(acc, u2); \
    } \
    out[(size_t)p_ * 64 + d] = fmaxf(acc, 0.f); }

  LOADQ(A, pb)
  #pragma unroll 1
  for (int k = 0; k < 8; k += 2) {
    LOADQ(B, pb + k + 1)
    COMPQ(A, pb + k)
    if (k < 6) LOADQ(A, pb + k + 2)
    COMPQ(B, pb + k + 1)
  }
}

// ---------------- launch ----------------

extern "C" void kernel_launch(void* const* d_in, const int* in_sizes, int n_in,
                              void* d_out, int out_size, void* d_ws, size_t ws_size,
                              hipStream_t stream) {
  const float* px    = (const float*)d_in[0];
  const float* py    = (const float*)d_in[1];
  const float* pz    = (const float*)d_in[2];
  const float* pi    = (const float*)d_in[3];
  const int*   npp   = (const int*)d_in[4];
  const int*   coors = (const int*)d_in[5];
  const float* W     = (const float*)d_in[6];
  const float* gamma = (const float*)d_in[7];
  const float* beta  = (const float*)d_in[8];
  float* out = (float*)d_out;

  float* wsf      = (float*)d_ws;
  float* partials = wsf;                    // 2500*54 = 135000 floats
  float* moments  = wsf + 135000;           // 54
  float* scale    = wsf + 135072;           // 64
  float* shift    = wsf + 135136;           // 64
  float* means    = wsf + 135232;           // 4*P_N floats (x,y,z,pad)

  k_moments<<<NB1, 256, 0, stream>>>(px, py, pz, pi, npp, coors, partials, means);
  k_red<<<54, 256, 0, stream>>>(partials, moments);
  k_stats<<<1, 64, 0, stream>>>(moments, W, gamma, beta, scale, shift);
  k_out<<<P_N / 32, 256, 0, stream>>>(px, py, pz, pi, npp, coors, W, scale, shift, means, out);
}

// Round 4
// 70.251 us; speedup vs baseline: 2.8722x; 1.7547x over previous
//
#include <hip/hip_runtime.h>

#define P_N 40000
#define M_N 100
#define NB1 2500   // k_moments blocks (4 waves; each wave handles 4 pillars)

typedef _Float16 half2_t __attribute__((ext_vector_type(2)));

__device__ __forceinline__ float bcf(int x) { return __int_as_float(x); }
__device__ __forceinline__ int   bci(float x) { return __float_as_int(x); }
__device__ __forceinline__ float rlf(float v, int l) {
  return bcf(__builtin_amdgcn_readlane(bci(v), l));
}

// DPP full-wave64 add-reduce on the VALU pipe (no LDS). Lane 63 holds the sum.
__device__ __forceinline__ float dpp_sum64(float x) {
  x += bcf(__builtin_amdgcn_update_dpp(0, bci(x), 0x111, 0xf, 0xf, true)); // row_shr:1
  x += bcf(__builtin_amdgcn_update_dpp(0, bci(x), 0x112, 0xf, 0xf, true)); // row_shr:2
  x += bcf(__builtin_amdgcn_update_dpp(0, bci(x), 0x114, 0xf, 0xf, true)); // row_shr:4
  x += bcf(__builtin_amdgcn_update_dpp(0, bci(x), 0x118, 0xf, 0xf, true)); // row_shr:8
  x += bcf(__builtin_amdgcn_update_dpp(0, bci(x), 0x142, 0xf, 0xf, true)); // row_bcast:15
  x += bcf(__builtin_amdgcn_update_dpp(0, bci(x), 0x143, 0xf, 0xf, true)); // row_bcast:31
  return x;
}

// ---------------- Kernel 1: per-pillar means + global feature moments ----------------

__device__ __forceinline__ void acc_point(float (&a1)[9], float (&a2)[45], const float f[9]) {
  #pragma unroll
  for (int c = 0; c < 9; ++c) a1[c] += f[c];
  int k = 0;
  #pragma unroll
  for (int c = 0; c < 9; ++c) {
    #pragma unroll
    for (int c2 = c; c2 < 9; ++c2) {
      a2[k] = fmaf(f[c], f[c2], a2[k]);
      ++k;
    }
  }
}

__global__ __launch_bounds__(256) void k_moments(
    const float* __restrict__ px, const float* __restrict__ py,
    const float* __restrict__ pz, const float* __restrict__ pi,
    const int* __restrict__ npp, const int* __restrict__ coors,
    float* __restrict__ partials, float* __restrict__ means)
{
  const int lane = threadIdx.x & 63;
  const int wid  = threadIdx.x >> 6;

  float a1[9] = {};
  float a2[45] = {};

  const bool act = lane < 50;
  const int pbase = __builtin_amdgcn_readfirstlane(blockIdx.x * 4 + wid);

  float2 X[4], Y[4], Z[4], I[4];
  int  N[4];
  int4 C[4];

  #pragma unroll
  for (int it = 0; it < 4; ++it) {
    const int p_ = pbase + it * 10000;
    X[it] = make_float2(0.f, 0.f); Y[it] = make_float2(0.f, 0.f);
    Z[it] = make_float2(0.f, 0.f); I[it] = make_float2(0.f, 0.f);
    if (act) {
      X[it] = ((const float2*)(px + (size_t)p_ * M_N))[lane];
      Y[it] = ((const float2*)(py + (size_t)p_ * M_N))[lane];
      Z[it] = ((const float2*)(pz + (size_t)p_ * M_N))[lane];
      I[it] = ((const float2*)(pi + (size_t)p_ * M_N))[lane];
    }
    N[it] = npp[p_];
    C[it] = ((const int4*)coors)[p_];
  }

  #pragma unroll
  for (int it = 0; it < 4; ++it) {
    const int p_ = pbase + it * 10000;
    // full (unmasked) row sums for the means — DPP reduce, broadcast from lane 63
    float sx = X[it].x + X[it].y;
    float sy = Y[it].x + Y[it].y;
    float sz = Z[it].x + Z[it].y;
    sx = dpp_sum64(sx); sy = dpp_sum64(sy); sz = dpp_sum64(sz);
    const int n  = N[it];
    const int nc = n < 1 ? 1 : n;
    const float inv = 1.f / (float)nc;
    const float mx = rlf(sx, 63) * inv;
    const float my = rlf(sy, 63) * inv;
    const float mz = rlf(sz, 63) * inv;

    const float xb = fmaf((float)C[it].w, 0.16f, 0.08f);            // X0 = 0
    const float yb = fmaf((float)C[it].z, 0.16f, 0.08f - 39.68f);   // Y0 = -39.68

    if (lane == 0) ((float4*)means)[p_] = make_float4(mx, my, mz, 0.f);

    if (2 * lane < n) {
      float f[9] = {X[it].x, Y[it].x, Z[it].x, I[it].x,
                    X[it].x - mx, Y[it].x - my, Z[it].x - mz, xb, yb};
      acc_point(a1, a2, f);
    }
    if (2 * lane + 1 < n) {
      float f[9] = {X[it].y, Y[it].y, Z[it].y, I[it].y,
                    X[it].y - mx, Y[it].y - my, Z[it].y - mz, xb, yb};
      acc_point(a1, a2, f);
    }
  }

  // wave-reduce all 54 accumulators on the VALU pipe
  #pragma unroll
  for (int i = 0; i < 9; ++i)  a1[i] = dpp_sum64(a1[i]);
  #pragma unroll
  for (int i = 0; i < 45; ++i) a2[i] = dpp_sum64(a2[i]);

  __shared__ float red[4][54];
  if (lane == 63) {
    #pragma unroll
    for (int i = 0; i < 9; ++i)  red[wid][i]     = a1[i];
    #pragma unroll
    for (int i = 0; i < 45; ++i) red[wid][9 + i] = a2[i];
  }
  __syncthreads();
  if (threadIdx.x < 54) {
    const int t = threadIdx.x;
    // transposed: channel-major so k_red reads contiguously
    partials[t * NB1 + blockIdx.x] = red[0][t] + red[1][t] + red[2][t] + red[3][t];
  }
}

// ---------------- Kernel 1b: reduce partials -> 54 moments ----------------

__global__ __launch_bounds__(256) void k_red(
    const float* __restrict__ partials, float* __restrict__ moments)
{
  const int c = blockIdx.x;
  float s = 0.f;
  for (int b = threadIdx.x; b < NB1; b += 256) s += partials[c * NB1 + b];
  s = dpp_sum64(s);
  __shared__ float r4[4];
  const int lane = threadIdx.x & 63, wid = threadIdx.x >> 6;
  if (lane == 63) r4[wid] = s;
  __syncthreads();
  if (threadIdx.x == 0) moments[c] = r4[0] + r4[1] + r4[2] + r4[3];
}

// ---------------- Kernel 2: moments -> per-channel BN scale/shift ----------------

__global__ __launch_bounds__(64) void k_stats(
    const float* __restrict__ moments, const float* __restrict__ W,
    const float* __restrict__ gamma, const float* __restrict__ beta,
    float* __restrict__ scale, float* __restrict__ shift)
{
  const int d = threadIdx.x;
  float mom[54];
  #pragma unroll
  for (int i = 0; i < 54; ++i) mom[i] = moments[i];

  float w[9];
  #pragma unroll
  for (int c = 0; c < 9; ++c) w[c] = W[c * 64 + d];
  const float invN = 1.f / ((float)P_N * (float)M_N);
  float mu = 0.f;
  #pragma unroll
  for (int c = 0; c < 9; ++c) mu += mom[c] * w[c];
  mu *= invN;
  float e2 = 0.f;
  int k = 0;
  #pragma unroll
  for (int c = 0; c < 9; ++c) {
    #pragma unroll
    for (int c2 = c; c2 < 9; ++c2) {
      const float t = w[c] * w[c2] * mom[9 + k];
      e2 += (c == c2) ? t : 2.f * t;
      ++k;
    }
  }
  e2 *= invN;
  float var = e2 - mu * mu;
  var = var < 0.f ? 0.f : var;
  const float sc = gamma[d] * rsqrtf(var + 1e-5f);
  const float sh = fmaf(-mu, sc, beta[d]);
  scale[d] = sc;
  shift[d] = sh;
}

// ---------------- Kernel 3: fused linear+BN+ReLU+max ----------------
// wave = pillar PAIR: lanes 0-24 load pillar A's rows (float4), lanes 32-56
// pillar B's (contiguous 800B). Points packed to f16 pairs; two broadcast
// passes (readlane from half A then half B) using v_dot2_f32_f16.

__device__ __forceinline__ float dot2pt(int pxy, int pzi, int src_lane,
                                        half2_t hAB, half2_t hCD, float sE) {
  const int axy = __builtin_amdgcn_readlane(pxy, src_lane);
  const int azi = __builtin_amdgcn_readlane(pzi, src_lane);
  float t = __builtin_amdgcn_fdot2(__builtin_bit_cast(half2_t, axy), hAB, sE, false);
  return  __builtin_amdgcn_fdot2(__builtin_bit_cast(half2_t, azi), hCD, t, false);
}

__global__ __launch_bounds__(256) void k_out(
    const float* __restrict__ px, const float* __restrict__ py,
    const float* __restrict__ pz, const float* __restrict__ pi,
    const int* __restrict__ npp, const int* __restrict__ coors,
    const float* __restrict__ W, const float* __restrict__ scale,
    const float* __restrict__ shift, const float* __restrict__ means,
    float* __restrict__ out)
{
  const int lane = threadIdx.x & 63;
  const int wid  = threadIdx.x >> 6;
  const int ll   = lane & 31;
  const int d    = lane;

  const int p0 = __builtin_amdgcn_readfirstlane((blockIdx.x * 4 + wid) * 2);
  const int ph = p0 + (lane >> 5);

  float4 vx = make_float4(0,0,0,0), vy = vx, vz = vx, vi = vx;
  if (ll < 25) {
    vx = ((const float4*)(px + (size_t)ph * M_N))[ll];
    vy = ((const float4*)(py + (size_t)ph * M_N))[ll];
    vz = ((const float4*)(pz + (size_t)ph * M_N))[ll];
    vi = ((const float4*)(pi + (size_t)ph * M_N))[ll];
  }
  const int    n_h = npp[ph];
  const int4   c4  = ((const int4*)coors)[ph];
  const float4 m4  = ((const float4*)means)[ph];

  // pack points: (x,y) and (z,i) as f16 pairs
  int hxy[4], hzi[4];
  hxy[0] = __builtin_bit_cast(int, __builtin_amdgcn_cvt_pkrtz(vx.x, vy.x));
  hxy[1] = __builtin_bit_cast(int, __builtin_amdgcn_cvt_pkrtz(vx.y, vy.y));
  hxy[2] = __builtin_bit_cast(int, __builtin_amdgcn_cvt_pkrtz(vx.z, vy.z));
  hxy[3] = __builtin_bit_cast(int, __builtin_amdgcn_cvt_pkrtz(vx.w, vy.w));
  hzi[0] = __builtin_bit_cast(int, __builtin_amdgcn_cvt_pkrtz(vz.x, vi.x));
  hzi[1] = __builtin_bit_cast(int, __builtin_amdgcn_cvt_pkrtz(vz.y, vi.y));
  hzi[2] = __builtin_bit_cast(int, __builtin_amdgcn_cvt_pkrtz(vz.z, vi.z));
  hzi[3] = __builtin_bit_cast(int, __builtin_amdgcn_cvt_pkrtz(vz.w, vi.w));

  const float sc = scale[d], sh = shift[d];
  float w[9];
  #pragma unroll
  for (int c = 0; c < 9; ++c) w[c] = W[c * 64 + d];
  const float sA = sc * (w[0] + w[4]);
  const float sB = sc * (w[1] + w[5]);
  const float sC = sc * (w[2] + w[6]);
  const float sD = sc * w[3];
  const float s4 = sc * w[4], s5 = sc * w[5], s6 = sc * w[6];
  const float s7 = sc * w[7], s8 = sc * w[8];
  half2_t hAB; hAB.x = (_Float16)sA; hAB.y = (_Float16)sB;
  half2_t hCD; hCD.x = (_Float16)sC; hCD.y = (_Float16)sD;

  #pragma unroll
  for (int pass = 0; pass < 2; ++pass) {
    const int OFF = pass * 32;
    const int n  = __builtin_amdgcn_readlane(n_h, OFF);
    const int q2 = __builtin_amdgcn_readlane(c4.z, OFF);
    const int q3 = __builtin_amdgcn_readlane(c4.w, OFF);
    const float mx = rlf(m4.x, OFF), my = rlf(m4.y, OFF), mz = rlf(m4.z, OFF);
    const float xb = fmaf((float)q3, 0.16f, 0.08f);
    const float yb = fmaf((float)q2, 0.16f, 0.08f - 39.68f);
    float sE = sh;
    sE = fmaf(-mx, s4, sE); sE = fmaf(-my, s5, sE); sE = fmaf(-mz, s6, sE);
    sE = fmaf( xb, s7, sE); sE = fmaf( yb, s8, sE);

    const int v = n < M_N ? n : M_N;
    float acc = (v < M_N) ? sh : -3.0e38f;   // masked points contribute shift
    const int v4f = v >> 2, rem = v & 3;

    for (int c = 0; c < v4f; ++c) {
      const int idx = OFF + c;
      const float t0 = dot2pt(hxy[0], hzi[0], idx, hAB, hCD, sE);
      const float t1 = dot2pt(hxy[1], hzi[1], idx, hAB, hCD, sE);
      const float t2 = dot2pt(hxy[2], hzi[2], idx, hAB, hCD, sE);
      const float t3 = dot2pt(hxy[3], hzi[3], idx, hAB, hCD, sE);
      acc = fmaxf(fmaxf(fmaxf(fmaxf(acc, t0), t1), t2), t3);
    }
    if (rem) {
      const int idx = OFF + v4f;
      acc = fmaxf(acc, dot2pt(hxy[0], hzi[0], idx, hAB, hCD, sE));
      if (rem > 1) acc = fmaxf(acc, dot2pt(hxy[1], hzi[1], idx, hAB, hCD, sE));
      if (rem > 2) acc = fmaxf(acc, dot2pt(hxy[2], hzi[2], idx, hAB, hCD, sE));
    }
    // max(relu) == relu(max)
    out[(size_t)(p0 + pass) * 64 + d] = fmaxf(acc, 0.f);
  }
}

// ---------------- launch ----------------

extern "C" void kernel_launch(void* const* d_in, const int* in_sizes, int n_in,
                              void* d_out, int out_size, void* d_ws, size_t ws_size,
                              hipStream_t stream) {
  const float* px    = (const float*)d_in[0];
  const float* py    = (const float*)d_in[1];
  const float* pz    = (const float*)d_in[2];
  const float* pi    = (const float*)d_in[3];
  const int*   npp   = (const int*)d_in[4];
  const int*   coors = (const int*)d_in[5];
  const float* W     = (const float*)d_in[6];
  const float* gamma = (const float*)d_in[7];
  const float* beta  = (const float*)d_in[8];
  float* out = (float*)d_out;

  float* wsf      = (float*)d_ws;
  float* partials = wsf;                    // 54*NB1 = 135000 floats (channel-major)
  float* moments  = wsf + 135000;           // 54
  float* scale    = wsf + 135072;           // 64
  float* shift    = wsf + 135136;           // 64
  float* means    = wsf + 135232;           // 4*P_N floats (x,y,z,pad)

  k_moments<<<NB1, 256, 0, stream>>>(px, py, pz, pi, npp, coors, partials, means);
  k_red<<<54, 256, 0, stream>>>(partials, moments);
  k_stats<<<1, 64, 0, stream>>>(moments, W, gamma, beta, scale, shift);
  k_out<<<P_N / 8, 256, 0, stream>>>(px, py, pz, pi, npp, coors, W, scale, shift, means, out);
}